// Round 17
// baseline (302.731 us; speedup 1.0000x reference)
//
#include <hip/hip_runtime.h>
#include <hip/hip_bf16.h>

// Problem constants
#define BN_TOK 2400     // B*N = 8*300
#define QDIM   256
#define NG     4
#define FLAT   32768    // G * (EOUT*POUT) = 4*8192
#define GSZ    8192
#define KSP    16       // split-K ways for gemm2
#define LN_EPS 1e-5f
#define PPAD   42       // o1T row stride (ushorts): 21 dwords, odd -> conflict-free reads

typedef __attribute__((ext_vector_type(8))) short bf16x8;
typedef __attribute__((ext_vector_type(4))) float f32x4;
typedef __hip_bfloat16 bf16;

__device__ __forceinline__ float bf2f(ushort u) {
  union { unsigned int i; float f; } c;
  c.i = ((unsigned int)u) << 16;
  return c.f;
}
__device__ __forceinline__ ushort f2u(float f) {
  bf16 h = __float2bfloat16(f);
  union { bf16 h; ushort u; } c; c.h = h; return c.u;
}

// bijective XCD-chunked swizzle (m204)
__device__ __forceinline__ int xcdswz(int orig, int nwg) {
  int xcd = orig & 7, base = orig >> 3;
  int q = nwg >> 3, r = nwg & 7;
  int start = (xcd < r) ? xcd * (q + 1) : r * (q + 1) + (xcd - r) * q;
  return start + base;
}

// ---------------------------------------------------------------- fp32 -> bf16 cast
__global__ __launch_bounds__(256) void cast_k(const float* __restrict__ in,
                                              bf16* __restrict__ out, int n4) {
  int i = blockIdx.x * 256 + threadIdx.x;
  if (i < n4) {
    float4 v = ((const float4*)in)[i];
    bf16 tmp[4] = {__float2bfloat16(v.x), __float2bfloat16(v.y),
                   __float2bfloat16(v.z), __float2bfloat16(v.w)};
    ((ushort4*)out)[i] = *(const ushort4*)tmp;
  }
}

// ---------------------------------------------------------------- build W_eff + bias_eff (separable form)
__global__ __launch_bounds__(256) void build_weff_k(
    const float* __restrict__ cpg_w, const float* __restrict__ cpg_b,
    const float* __restrict__ ppg_w, const float* __restrict__ ppg_b,
    const float* __restrict__ ml, const float* __restrict__ mr,
    const float* __restrict__ sl, const float* __restrict__ sr,
    bf16* __restrict__ Weff, float* __restrict__ bias_eff) {
  int tid = threadIdx.x;
  int rb = blockIdx.x;
  int g = blockIdx.y;
  int part = blockIdx.z;
  int pbase = part * 256 + g * 64;

  float pw[64];
#pragma unroll
  for (int kl = 0; kl < 64; ++kl)
    pw[kl] = ppg_w[(size_t)(pbase + kl) * QDIM + tid];

  if (part == 0) {
    int d = rb;
    float t[8];
#pragma unroll
    for (int k = 0; k < 8; ++k) {
      float s = 0.f;
#pragma unroll
      for (int l = 0; l < 8; ++l) s += mr[g * 512 + l * 64 + d] * pw[k * 8 + l];
      t[k] = s;
    }
    for (int r = 0; r < 64; ++r) {
      int outrow = g * GSZ + d * 64 + r;
      int srcrow = g * GSZ + r * 64 + d;
      float acc = cpg_w[(size_t)srcrow * QDIM + tid];
#pragma unroll
      for (int k = 0; k < 8; ++k) acc += ml[g * 512 + r * 8 + k] * t[k];
      Weff[(size_t)outrow * QDIM + tid] = __float2bfloat16(acc);
    }
    if (tid < 64) {
      int r = tid;
      float b = cpg_b[g * GSZ + r * 64 + d];
#pragma unroll
      for (int k = 0; k < 8; ++k) {
        float s = 0.f;
#pragma unroll
        for (int l = 0; l < 8; ++l)
          s += mr[g * 512 + l * 64 + d] * ppg_b[pbase + k * 8 + l];
        b += ml[g * 512 + r * 8 + k] * s;
      }
      bias_eff[g * GSZ + d * 64 + r] = b;
    }
  } else {
    int o0 = rb * 2;
    float t0v[8], t1v[8];
#pragma unroll
    for (int l = 0; l < 8; ++l) {
      float s0 = 0.f, s1 = 0.f;
#pragma unroll
      for (int k = 0; k < 8; ++k) {
        s0 += sl[g * 1024 + o0 * 8 + k] * pw[k * 8 + l];
        s1 += sl[g * 1024 + (o0 + 1) * 8 + k] * pw[k * 8 + l];
      }
      t0v[l] = s0; t1v[l] = s1;
    }
    for (int r = 0; r < 32; ++r) {
      int rr = rb * 64 + r;
      int p = rr & 31;
      int row = g * GSZ + 4096 + rr;
      float acc = cpg_w[(size_t)row * QDIM + tid];
#pragma unroll
      for (int l = 0; l < 8; ++l) acc += sr[g * 256 + l * 32 + p] * t0v[l];
      Weff[(size_t)row * QDIM + tid] = __float2bfloat16(acc);
    }
    for (int r = 32; r < 64; ++r) {
      int rr = rb * 64 + r;
      int p = rr & 31;
      int row = g * GSZ + 4096 + rr;
      float acc = cpg_w[(size_t)row * QDIM + tid];
#pragma unroll
      for (int l = 0; l < 8; ++l) acc += sr[g * 256 + l * 32 + p] * t1v[l];
      Weff[(size_t)row * QDIM + tid] = __float2bfloat16(acc);
    }
    if (tid < 64) {
      int rr = rb * 64 + tid;
      int o = rr >> 5, p = rr & 31;
      int row = g * GSZ + 4096 + rr;
      float b = cpg_b[row];
#pragma unroll
      for (int l = 0; l < 8; ++l) {
        float s = 0.f;
#pragma unroll
        for (int k = 0; k < 8; ++k)
          s += sl[g * 1024 + o * 8 + k] * ppg_b[pbase + k * 8 + l];
        b += sr[g * 256 + l * 32 + p] * s;
      }
      bias_eff[row] = b;
    }
  }
}

// ---------------------------------------------------------------- W = base_w + lora_B@lora_A
__global__ __launch_bounds__(256) void build_wb_k(
    const float* __restrict__ base_w, const float* __restrict__ lora_A,
    const float* __restrict__ lora_B, bf16* __restrict__ Wb) {
  int jb = blockIdx.x * 256;
  int i0 = blockIdx.y * 16;
  int tid = threadIdx.x;
  __shared__ float lB[16][64];
  for (int e = tid; e < 16 * 64; e += 256)
    lB[e >> 6][e & 63] = lora_B[(size_t)(i0 + (e >> 6)) * 64 + (e & 63)];
  __syncthreads();
  int j = jb + tid;
  float acc[16] = {};
  for (int r = 0; r < 64; ++r) {
    float la = lora_A[(size_t)r * FLAT + j];
#pragma unroll
    for (int i = 0; i < 16; ++i) acc[i] += lB[i][r] * la;
  }
#pragma unroll
  for (int i = 0; i < 16; ++i)
    Wb[(size_t)(i0 + i) * FLAT + j] =
        __float2bfloat16(base_w[(size_t)(i0 + i) * FLAT + j] + acc[i]);
}

// ---------------------------------------------------------------- unified MFMA GEMM: C = A @ B^T (+bias)
// T3/T4 2-phase: double-buffered 64KB LDS, raw s_barrier + COUNTED vmcnt(8)
// (prefetch loads stay in flight across barriers - never drain to 0 in loop).
// BK=64 both-sides XOR swizzle; XCD swizzle; __launch_bounds__(256,4).
// OBF: C-stage in XOR-swizzled LDS tile (aliases buf0) -> coalesced store-out.
template <bool OBF>
__global__ __launch_bounds__(256, 4) void gemm_nt(
    const bf16* __restrict__ A, const bf16* __restrict__ B,
    const float* __restrict__ bias, void* __restrict__ Cout,
    int M, int lda, int ldb, int Kslice, int ldc) {
  __shared__ __align__(16) ushort smem[32768];  // 64KB: 2 x (As 8192 | Bs 8192)
  int tid = threadIdx.x;
  int w = tid >> 6, lane = tid & 63;
  int nwg = gridDim.x * gridDim.y;
  int swz = xcdswz(blockIdx.x + gridDim.x * blockIdx.y, nwg);
  int m0 = (swz % gridDim.x) * 128, n0 = (swz / gridDim.x) * 128;
  int kbase = blockIdx.z * Kslice;
  int wm = (w & 1) * 64, wn = (w >> 1) * 64;

  auto stage = [&](int buf, int kk) {   // issues exactly 8 global_load_lds per thread
    ushort* As = smem + buf * 16384;
    ushort* Bs = As + 8192;
#pragma unroll
    for (int i = 0; i < 4; ++i) {
      int c = (i * 4 + w) * 64 + lane;
      int row = c >> 3, slot = c & 7;
      int ss = slot ^ (row & 7);
      int grow = m0 + row; if (grow >= M) grow = M - 1;
      const bf16* srcA = A + (size_t)grow * lda + kk + ss * 8;
      __builtin_amdgcn_global_load_lds(
          (const __attribute__((address_space(1))) void*)srcA,
          (__attribute__((address_space(3))) void*)(As + (size_t)c * 8), 16, 0, 0);
      const bf16* srcB = B + (size_t)(n0 + row) * ldb + kk + ss * 8;
      __builtin_amdgcn_global_load_lds(
          (const __attribute__((address_space(1))) void*)srcB,
          (__attribute__((address_space(3))) void*)(Bs + (size_t)c * 8), 16, 0, 0);
    }
  };

  f32x4 acc[4][4] = {};
  int nt = Kslice >> 6;
  stage(0, kbase);
  int cur = 0;
  for (int t = 0; t < nt; ++t) {
    if (t + 1 < nt) {
      stage(cur ^ 1, kbase + (t + 1) * 64);        // 8 prefetch loads in flight
      asm volatile("s_waitcnt vmcnt(8)" ::: "memory");  // cur's 8 (oldest) landed
    } else {
      asm volatile("s_waitcnt vmcnt(0)" ::: "memory");
    }
    __builtin_amdgcn_s_barrier();                  // all waves: cur fully staged
    __builtin_amdgcn_sched_barrier(0);
    const ushort* As = smem + cur * 16384;
    const ushort* Bs = As + 8192;
#pragma unroll
    for (int ks = 0; ks < 2; ++ks) {
      int sl = ks * 4 + (lane >> 4);
      bf16x8 af[4], bfr[4];
#pragma unroll
      for (int i = 0; i < 4; ++i) {
        int r = wm + i * 16 + (lane & 15);
        af[i] = *(const bf16x8*)&As[r * 64 + (sl ^ (r & 7)) * 8];
        int cc = wn + i * 16 + (lane & 15);
        bfr[i] = *(const bf16x8*)&Bs[cc * 64 + (sl ^ (cc & 7)) * 8];
      }
#pragma unroll
      for (int i = 0; i < 4; ++i)
#pragma unroll
        for (int j = 0; j < 4; ++j)
          acc[i][j] = __builtin_amdgcn_mfma_f32_16x16x32_bf16(bfr[j], af[i], acc[i][j], 0, 0, 0);
    }
    __builtin_amdgcn_sched_barrier(0);
    __builtin_amdgcn_s_barrier();                  // all waves done reading cur
    cur ^= 1;
  }

  if constexpr (OBF) {
    // C-stage in buf0 region: rows of 128 ushorts, col XOR-swizzled (T2 pattern)
#pragma unroll
    for (int i = 0; i < 4; ++i) {
      int row = wm + i * 16 + (lane & 15);
#pragma unroll
      for (int j = 0; j < 4; ++j) {
        int nl = wn + j * 16 + (lane >> 4) * 4;
        float4 b4 = bias ? *(const float4*)&bias[n0 + nl] : make_float4(0.f, 0.f, 0.f, 0.f);
        ushort4 uv = {f2u(acc[i][j][0] + b4.x), f2u(acc[i][j][1] + b4.y),
                      f2u(acc[i][j][2] + b4.z), f2u(acc[i][j][3] + b4.w)};
        *(ushort4*)&smem[row * 128 + (nl ^ ((row & 7) << 3))] = uv;
      }
    }
    __syncthreads();
    bf16* co = (bf16*)Cout;
#pragma unroll
    for (int it = 0; it < 8; ++it) {
      int row = it * 16 + (tid >> 4);     // 16 lanes per row -> 256B contiguous runs
      int sub = (tid & 15) * 8;
      int gm = m0 + row;
      if (gm < M) {
        *(bf16x8*)(co + ((size_t)blockIdx.z * M + gm) * ldc + n0 + sub) =
            *(const bf16x8*)&smem[row * 128 + (sub ^ ((row & 7) << 3))];
      }
    }
  } else {
#pragma unroll
    for (int i = 0; i < 4; ++i) {
      int m = m0 + wm + i * 16 + (lane & 15);
      if (m >= M) continue;
      size_t ro = (size_t)blockIdx.z * M + m;
#pragma unroll
      for (int j = 0; j < 4; ++j) {
        int nb = n0 + wn + j * 16 + (lane >> 4) * 4;
        float4 b4 = bias ? *(const float4*)&bias[nb] : make_float4(0.f, 0.f, 0.f, 0.f);
        *(float4*)((float*)Cout + ro * ldc + nb) =
            make_float4(acc[i][j][0] + b4.x, acc[i][j][1] + b4.y,
                        acc[i][j][2] + b4.z, acc[i][j][3] + b4.w);
      }
    }
  }
}

// ---------------------------------------------------------------- chain: fully LDS-staged I/O
__device__ __forceinline__ void block_red2(float& s, float& sq, float* redS,
                                           float* redQ, int tid) {
#pragma unroll
  for (int off = 32; off > 0; off >>= 1) {
    s += __shfl_down(s, off);
    sq += __shfl_down(sq, off);
  }
  int w = tid >> 6;
  if ((tid & 63) == 0) { redS[w] = s; redQ[w] = sq; }
  __syncthreads();
  s = redS[0] + redS[1] + redS[2] + redS[3];
  sq = redQ[0] + redQ[1] + redQ[2] + redQ[3];
}

// LDS layout (ushorts): Mt[64][72] @0 (4608) | Ss[128][40] @4608 (5120)
//                       xbs[32][72] @9728 (2304) | o1T[64][PPAD] @12032 (2688)
// O2[128][72] aliases @0 (max 9207 < 9728; Mt+Ss dead by then)
__global__ __launch_bounds__(256) void chain_k(
    const float* __restrict__ x, bf16* __restrict__ common) {
  int tid = threadIdx.x;
  int tl = blockIdx.x;
  int g = blockIdx.y;
  int lane = tid & 63, w = tid >> 6;

  __shared__ __align__(16) ushort sm[14720];  // 29.4 KB
  __shared__ float redS[4], redQ[4];
  ushort* Mt = sm;
  ushort* Ss = sm + 4608;
  ushort* xbs = sm + 9728;
  ushort* o1Tb = sm + 12032;

  bf16* cm = common + (size_t)tl * FLAT + g * GSZ;
  const ushort* cmu = (const ushort*)cm;
  const float* xg = x + ((size_t)tl * NG + g) * 2048;

  // ---- coalesced stage: M-part, S-part (16B/lane), x (fp32 -> bf16)
#pragma unroll
  for (int it = 0; it < 2; ++it) {
    int idx = it * 256 + tid;
    int e = idx * 8;
    { // M: [d][c] rows of 64
      bf16x8 v = *(const bf16x8*)&cmu[e];
      *(bf16x8*)&Mt[(e >> 6) * 72 + (e & 63)] = v;
    }
    { // S: [o][p] rows of 32
      bf16x8 v = *(const bf16x8*)&cmu[4096 + e];
      *(bf16x8*)&Ss[(e >> 5) * 40 + (e & 31)] = v;
    }
    { // x: [p][c] rows of 64, fp32->bf16
      int fi = it * 256 + tid;           // float4 index 0..511
      float4 v = ((const float4*)xg)[fi];
      int fl = fi * 4;
      ushort4 u = {f2u(v.x), f2u(v.y), f2u(v.z), f2u(v.w)};
      *(ushort4*)&xbs[(fl >> 6) * 72 + (fl & 63)] = u;
    }
  }
  __syncthreads();

  // ---- out1^T[d][p] = sum_c M^T[d][c] * x[p][c]
  int dlane = w * 16 + (lane & 15);
  f32x4 a1[2] = {};
#pragma unroll
  for (int ks = 0; ks < 2; ++ks) {
    bf16x8 af = *(const bf16x8*)&Mt[dlane * 72 + ks * 32 + (lane >> 4) * 8];
#pragma unroll
    for (int pt = 0; pt < 2; ++pt) {
      int p = pt * 16 + (lane & 15);
      bf16x8 bx = *(const bf16x8*)&xbs[p * 72 + ks * 32 + (lane >> 4) * 8];
      a1[pt] = __builtin_amdgcn_mfma_f32_16x16x32_bf16(af, bx, a1[pt], 0, 0, 0);
    }
  }
  // ---- LN1 over 2048 + relu -> o1^T bf16
  {
    float s = 0.f, sq = 0.f;
#pragma unroll
    for (int pt = 0; pt < 2; ++pt)
#pragma unroll
      for (int r = 0; r < 4; ++r) { float v = a1[pt][r]; s += v; sq += v * v; }
    block_red2(s, sq, redS, redQ, tid);
    float mean = s * (1.f / 2048.f);
    float var = sq * (1.f / 2048.f) - mean * mean;
    float rs = rsqrtf(var + LN_EPS);
#pragma unroll
    for (int pt = 0; pt < 2; ++pt)
#pragma unroll
      for (int r = 0; r < 4; ++r) {
        float v = (a1[pt][r] - mean) * rs;
        if (v < 0.f) v = 0.f;
        int d = w * 16 + (lane >> 4) * 4 + r;
        int p = pt * 16 + (lane & 15);
        o1Tb[d * PPAD + p] = f2u(v);
      }
  }
  __syncthreads();

  // ---- out2[o][d] = sum_p S[o][p] * o1^T[d][p]
  f32x4 a2[2][4] = {};
  {
    bf16x8 bfd[4];
#pragma unroll
    for (int dj = 0; dj < 4; ++dj)
      bfd[dj] = *(const bf16x8*)&o1Tb[(dj * 16 + (lane & 15)) * PPAD + (lane >> 4) * 8];
#pragma unroll
    for (int oi = 0; oi < 2; ++oi) {
      int o = (2 * w + oi) * 16 + (lane & 15);
      bf16x8 sf = *(const bf16x8*)&Ss[o * 40 + (lane >> 4) * 8];
#pragma unroll
      for (int dj = 0; dj < 4; ++dj)
        a2[oi][dj] = __builtin_amdgcn_mfma_f32_16x16x32_bf16(bfd[dj], sf, a2[oi][dj], 0, 0, 0);
    }
  }
  // ---- LN2 over 8192 + relu -> O2 LDS (aliases Mt/Ss) -> coalesced global write
  {
    float s = 0.f, sq = 0.f;
#pragma unroll
    for (int oi = 0; oi < 2; ++oi)
#pragma unroll
      for (int dj = 0; dj < 4; ++dj)
#pragma unroll
        for (int r = 0; r < 4; ++r) { float v = a2[oi][dj][r]; s += v; sq += v * v; }
    block_red2(s, sq, redS, redQ, tid);   // internal barrier: all Ss reads complete after this
    float mean = s * (1.f / 8192.f);
    float var = sq * (1.f / 8192.f) - mean * mean;
    float rs = rsqrtf(var + LN_EPS);
#pragma unroll
    for (int oi = 0; oi < 2; ++oi) {
      int o = (2 * w + oi) * 16 + (lane & 15);
#pragma unroll
      for (int dj = 0; dj < 4; ++dj) {
        int d0 = dj * 16 + (lane >> 4) * 4;
        ushort4 uv;
#pragma unroll
        for (int r = 0; r < 4; ++r) {
          float v = (a2[oi][dj][r] - mean) * rs;
          if (v < 0.f) v = 0.f;
          ((ushort*)&uv)[r] = f2u(v);
        }
        *(ushort4*)&sm[o * 72 + d0] = uv;   // O2[o][d] @ base 0
      }
    }
  }
  __syncthreads();
  {
    // write ALL 8192 ushorts of out2 (128 rows x 64 cols)
    ushort* cw = (ushort*)cm;
#pragma unroll
    for (int it = 0; it < 4; ++it) {
      int e = (it * 256 + tid) * 8;
      *(bf16x8*)&cw[e] = *(const bf16x8*)&sm[(e >> 6) * 72 + (e & 63)];
    }
  }
}

// ---------------------------------------------------------------- finish
__global__ __launch_bounds__(256) void finish_k(
    const float* __restrict__ partial, const float* __restrict__ query,
    const float* __restrict__ out_bias, const float* __restrict__ gamma,
    const float* __restrict__ beta, float* __restrict__ out, int t0, int M) {
  int tid = threadIdx.x;
  int tl = blockIdx.x;
  int t = t0 + tl;
  __shared__ float redS[4], redQ[4];
  float s = 0.f;
  for (int ks = 0; ks < KSP; ++ks)
    s += partial[((size_t)ks * M + tl) * QDIM + tid];
  float v = s + out_bias[tid] + query[(size_t)t * QDIM + tid];
  float sum = v, sqv = v * v;
  block_red2(sum, sqv, redS, redQ, tid);
  float mean = sum * (1.f / 256.f);
  float var = sqv * (1.f / 256.f) - mean * mean;
  out[(size_t)t * QDIM + tid] =
      (v - mean) * rsqrtf(var + LN_EPS) * gamma[tid] + beta[tid];
}

// ---------------------------------------------------------------- launch
extern "C" void kernel_launch(void* const* d_in, const int* in_sizes, int n_in,
                              void* d_out, int out_size, void* d_ws, size_t ws_size,
                              hipStream_t stream) {
  const float* x       = (const float*)d_in[1];
  const float* query   = (const float*)d_in[2];
  const float* cpg_w   = (const float*)d_in[3];
  const float* cpg_b   = (const float*)d_in[4];
  const float* ppg_w   = (const float*)d_in[5];
  const float* ppg_b   = (const float*)d_in[6];
  const float* ml      = (const float*)d_in[7];
  const float* mr      = (const float*)d_in[8];
  const float* sl      = (const float*)d_in[9];
  const float* sr      = (const float*)d_in[10];
  const float* base_w  = (const float*)d_in[11];
  const float* lora_A  = (const float*)d_in[12];
  const float* lora_B  = (const float*)d_in[13];
  const float* out_bias= (const float*)d_in[14];
  const float* gamma   = (const float*)d_in[15];
  const float* beta    = (const float*)d_in[16];
  float* out = (float*)d_out;

  float* wsf = (float*)d_ws;
  bf16*  Wb      = (bf16*)(wsf + 0);          // 256x32768 bf16 = 4,194,304 f
  bf16*  Weff    = (bf16*)(wsf + 4194304);    // 32768x256 bf16 = 4,194,304 f
  float* bias_eff= wsf + 8388608;             // 32,768 f
  bf16*  qb      = (bf16*)(wsf + 8421376);    // 2400x256 bf16 = 307,200 f
  size_t fixedF  = 8728576;
  int CT = (ws_size >= (fixedF + (size_t)BN_TOK * 20480) * sizeof(float)) ? BN_TOK : 600;
  int NCH = BN_TOK / CT;
  bf16*  commonb = (bf16*)(wsf + fixedF);
  float* partialb= wsf + fixedF + (size_t)CT * 16384;

  // prep (once per call)
  build_weff_k<<<dim3(64, NG, 2), 256, 0, stream>>>(
      cpg_w, cpg_b, ppg_w, ppg_b, ml, mr, sl, sr, Weff, bias_eff);
  cast_k<<<dim3(BN_TOK * QDIM / 4 / 256), 256, 0, stream>>>(query, qb, BN_TOK * QDIM / 4);
  build_wb_k<<<dim3(FLAT / 256, QDIM / 16), 256, 0, stream>>>(base_w, lora_A, lora_B, Wb);

  for (int ch = 0; ch < NCH; ++ch) {
    int t0 = ch * CT;
    gemm_nt<true><<<dim3((CT + 127) / 128, FLAT / 128, 1), 256, 0, stream>>>(
        qb + (size_t)t0 * QDIM, Weff, bias_eff, commonb, CT, QDIM, QDIM, QDIM, FLAT);
    chain_k<<<dim3(CT, NG), 256, 0, stream>>>(x + (size_t)t0 * GSZ, commonb);
    gemm_nt<false><<<dim3((CT + 127) / 128, QDIM / 128, KSP), 256, 0, stream>>>(
        commonb, Wb, nullptr, partialb, CT, FLAT, FLAT, FLAT / KSP, QDIM);
    finish_k<<<dim3(CT), 256, 0, stream>>>(partialb, query, out_bias, gamma, beta, out, t0, CT);
  }
}

// Round 18
// 278.502 us; speedup vs baseline: 1.0870x; 1.0870x over previous
//
#include <hip/hip_runtime.h>
#include <hip/hip_bf16.h>

// Problem constants
#define BN_TOK 2400     // B*N = 8*300
#define QDIM   256
#define NG     4
#define FLAT   32768    // G * (EOUT*POUT) = 4*8192
#define GSZ    8192
#define KSP    16       // split-K ways for gemm2
#define LN_EPS 1e-5f
#define PPAD   42       // o1T row stride (ushorts): 21 dwords, odd -> conflict-free reads

typedef __attribute__((ext_vector_type(8))) short bf16x8;
typedef __attribute__((ext_vector_type(4))) float f32x4;
typedef __hip_bfloat16 bf16;

__device__ __forceinline__ float bf2f(ushort u) {
  union { unsigned int i; float f; } c;
  c.i = ((unsigned int)u) << 16;
  return c.f;
}
__device__ __forceinline__ ushort f2u(float f) {
  bf16 h = __float2bfloat16(f);
  union { bf16 h; ushort u; } c; c.h = h; return c.u;
}

// bijective XCD-chunked swizzle (m204)
__device__ __forceinline__ int xcdswz(int orig, int nwg) {
  int xcd = orig & 7, base = orig >> 3;
  int q = nwg >> 3, r = nwg & 7;
  int start = (xcd < r) ? xcd * (q + 1) : r * (q + 1) + (xcd - r) * q;
  return start + base;
}

// ---------------------------------------------------------------- fp32 -> bf16 cast
__global__ __launch_bounds__(256) void cast_k(const float* __restrict__ in,
                                              bf16* __restrict__ out, int n4) {
  int i = blockIdx.x * 256 + threadIdx.x;
  if (i < n4) {
    float4 v = ((const float4*)in)[i];
    bf16 tmp[4] = {__float2bfloat16(v.x), __float2bfloat16(v.y),
                   __float2bfloat16(v.z), __float2bfloat16(v.w)};
    ((ushort4*)out)[i] = *(const ushort4*)tmp;
  }
}

// ---------------------------------------------------------------- build W_eff + bias_eff (separable form)
__global__ __launch_bounds__(256) void build_weff_k(
    const float* __restrict__ cpg_w, const float* __restrict__ cpg_b,
    const float* __restrict__ ppg_w, const float* __restrict__ ppg_b,
    const float* __restrict__ ml, const float* __restrict__ mr,
    const float* __restrict__ sl, const float* __restrict__ sr,
    bf16* __restrict__ Weff, float* __restrict__ bias_eff) {
  int tid = threadIdx.x;
  int rb = blockIdx.x;
  int g = blockIdx.y;
  int part = blockIdx.z;
  int pbase = part * 256 + g * 64;

  float pw[64];
#pragma unroll
  for (int kl = 0; kl < 64; ++kl)
    pw[kl] = ppg_w[(size_t)(pbase + kl) * QDIM + tid];

  if (part == 0) {
    int d = rb;
    float t[8];
#pragma unroll
    for (int k = 0; k < 8; ++k) {
      float s = 0.f;
#pragma unroll
      for (int l = 0; l < 8; ++l) s += mr[g * 512 + l * 64 + d] * pw[k * 8 + l];
      t[k] = s;
    }
    for (int r = 0; r < 64; ++r) {
      int outrow = g * GSZ + d * 64 + r;
      int srcrow = g * GSZ + r * 64 + d;
      float acc = cpg_w[(size_t)srcrow * QDIM + tid];
#pragma unroll
      for (int k = 0; k < 8; ++k) acc += ml[g * 512 + r * 8 + k] * t[k];
      Weff[(size_t)outrow * QDIM + tid] = __float2bfloat16(acc);
    }
    if (tid < 64) {
      int r = tid;
      float b = cpg_b[g * GSZ + r * 64 + d];
#pragma unroll
      for (int k = 0; k < 8; ++k) {
        float s = 0.f;
#pragma unroll
        for (int l = 0; l < 8; ++l)
          s += mr[g * 512 + l * 64 + d] * ppg_b[pbase + k * 8 + l];
        b += ml[g * 512 + r * 8 + k] * s;
      }
      bias_eff[g * GSZ + d * 64 + r] = b;
    }
  } else {
    int o0 = rb * 2;
    float t0v[8], t1v[8];
#pragma unroll
    for (int l = 0; l < 8; ++l) {
      float s0 = 0.f, s1 = 0.f;
#pragma unroll
      for (int k = 0; k < 8; ++k) {
        s0 += sl[g * 1024 + o0 * 8 + k] * pw[k * 8 + l];
        s1 += sl[g * 1024 + (o0 + 1) * 8 + k] * pw[k * 8 + l];
      }
      t0v[l] = s0; t1v[l] = s1;
    }
    for (int r = 0; r < 32; ++r) {
      int rr = rb * 64 + r;
      int p = rr & 31;
      int row = g * GSZ + 4096 + rr;
      float acc = cpg_w[(size_t)row * QDIM + tid];
#pragma unroll
      for (int l = 0; l < 8; ++l) acc += sr[g * 256 + l * 32 + p] * t0v[l];
      Weff[(size_t)row * QDIM + tid] = __float2bfloat16(acc);
    }
    for (int r = 32; r < 64; ++r) {
      int rr = rb * 64 + r;
      int p = rr & 31;
      int row = g * GSZ + 4096 + rr;
      float acc = cpg_w[(size_t)row * QDIM + tid];
#pragma unroll
      for (int l = 0; l < 8; ++l) acc += sr[g * 256 + l * 32 + p] * t1v[l];
      Weff[(size_t)row * QDIM + tid] = __float2bfloat16(acc);
    }
    if (tid < 64) {
      int rr = rb * 64 + tid;
      int o = rr >> 5, p = rr & 31;
      int row = g * GSZ + 4096 + rr;
      float b = cpg_b[row];
#pragma unroll
      for (int l = 0; l < 8; ++l) {
        float s = 0.f;
#pragma unroll
        for (int k = 0; k < 8; ++k)
          s += sl[g * 1024 + o * 8 + k] * ppg_b[pbase + k * 8 + l];
        b += sr[g * 256 + l * 32 + p] * s;
      }
      bias_eff[row] = b;
    }
  }
}

// ---------------------------------------------------------------- W = base_w + lora_B@lora_A
__global__ __launch_bounds__(256) void build_wb_k(
    const float* __restrict__ base_w, const float* __restrict__ lora_A,
    const float* __restrict__ lora_B, bf16* __restrict__ Wb) {
  int jb = blockIdx.x * 256;
  int i0 = blockIdx.y * 16;
  int tid = threadIdx.x;
  __shared__ float lB[16][64];
  for (int e = tid; e < 16 * 64; e += 256)
    lB[e >> 6][e & 63] = lora_B[(size_t)(i0 + (e >> 6)) * 64 + (e & 63)];
  __syncthreads();
  int j = jb + tid;
  float acc[16] = {};
  for (int r = 0; r < 64; ++r) {
    float la = lora_A[(size_t)r * FLAT + j];
#pragma unroll
    for (int i = 0; i < 16; ++i) acc[i] += lB[i][r] * la;
  }
#pragma unroll
  for (int i = 0; i < 16; ++i)
    Wb[(size_t)(i0 + i) * FLAT + j] =
        __float2bfloat16(base_w[(size_t)(i0 + i) * FLAT + j] + acc[i]);
}

// ---------------------------------------------------------------- unified MFMA GEMM: C = A @ B^T (+bias)
// Single-buffer staging (32KB LDS); BK=64 both-sides XOR swizzle; XCD swizzle.
// __launch_bounds__(256,4): cap regs at 128/wave (64 AGPR acc + <=64 VGPR)
// -> 4 blocks/CU resident. OBF: C-stage in XOR-swizzled LDS tile -> coalesced store-out.
template <bool OBF>
__global__ __launch_bounds__(256, 4) void gemm_nt(
    const bf16* __restrict__ A, const bf16* __restrict__ B,
    const float* __restrict__ bias, void* __restrict__ Cout,
    int M, int lda, int ldb, int Kslice, int ldc) {
  __shared__ __align__(16) ushort smem[16384];  // 32KB: As 8192 | Bs 8192; C-stage aliases
  ushort* As = smem;
  ushort* Bs = smem + 8192;
  int tid = threadIdx.x;
  int w = tid >> 6, lane = tid & 63;
  int nwg = gridDim.x * gridDim.y;
  int swz = xcdswz(blockIdx.x + gridDim.x * blockIdx.y, nwg);
  int m0 = (swz % gridDim.x) * 128, n0 = (swz / gridDim.x) * 128;
  int kbase = blockIdx.z * Kslice;
  int wm = (w & 1) * 64, wn = (w >> 1) * 64;
  f32x4 acc[4][4] = {};
  for (int kb = 0; kb < Kslice; kb += 64) {
#pragma unroll
    for (int i = 0; i < 4; ++i) {
      int c = (i * 4 + w) * 64 + lane;
      int row = c >> 3, slot = c & 7;
      int ss = slot ^ (row & 7);
      int grow = m0 + row; if (grow >= M) grow = M - 1;
      const bf16* srcA = A + (size_t)grow * lda + kbase + kb + ss * 8;
      __builtin_amdgcn_global_load_lds(
          (const __attribute__((address_space(1))) void*)srcA,
          (__attribute__((address_space(3))) void*)(As + (size_t)c * 8), 16, 0, 0);
      const bf16* srcB = B + (size_t)(n0 + row) * ldb + kbase + kb + ss * 8;
      __builtin_amdgcn_global_load_lds(
          (const __attribute__((address_space(1))) void*)srcB,
          (__attribute__((address_space(3))) void*)(Bs + (size_t)c * 8), 16, 0, 0);
    }
    __syncthreads();
#pragma unroll
    for (int ks = 0; ks < 2; ++ks) {
      int sl = ks * 4 + (lane >> 4);
      bf16x8 af[4], bfr[4];
#pragma unroll
      for (int i = 0; i < 4; ++i) {
        int r = wm + i * 16 + (lane & 15);
        af[i] = *(const bf16x8*)&As[r * 64 + (sl ^ (r & 7)) * 8];
        int cc = wn + i * 16 + (lane & 15);
        bfr[i] = *(const bf16x8*)&Bs[cc * 64 + (sl ^ (cc & 7)) * 8];
      }
#pragma unroll
      for (int i = 0; i < 4; ++i)
#pragma unroll
        for (int j = 0; j < 4; ++j)
          acc[i][j] = __builtin_amdgcn_mfma_f32_16x16x32_bf16(bfr[j], af[i], acc[i][j], 0, 0, 0);
    }
    __syncthreads();
  }

  if constexpr (OBF) {
    // C-stage: rows of 128 ushorts, col XOR-swizzled by (row&7)<<3 (T2 pattern)
#pragma unroll
    for (int i = 0; i < 4; ++i) {
      int row = wm + i * 16 + (lane & 15);
#pragma unroll
      for (int j = 0; j < 4; ++j) {
        int nl = wn + j * 16 + (lane >> 4) * 4;
        float4 b4 = bias ? *(const float4*)&bias[n0 + nl] : make_float4(0.f, 0.f, 0.f, 0.f);
        ushort4 uv = {f2u(acc[i][j][0] + b4.x), f2u(acc[i][j][1] + b4.y),
                      f2u(acc[i][j][2] + b4.z), f2u(acc[i][j][3] + b4.w)};
        *(ushort4*)&smem[row * 128 + (nl ^ ((row & 7) << 3))] = uv;
      }
    }
    __syncthreads();
    bf16* co = (bf16*)Cout;
#pragma unroll
    for (int it = 0; it < 8; ++it) {
      int row = it * 16 + (tid >> 4);     // 16 lanes per row -> 256B contiguous runs
      int sub = (tid & 15) * 8;
      int gm = m0 + row;
      if (gm < M) {
        *(bf16x8*)(co + ((size_t)blockIdx.z * M + gm) * ldc + n0 + sub) =
            *(const bf16x8*)&smem[row * 128 + (sub ^ ((row & 7) << 3))];
      }
    }
  } else {
#pragma unroll
    for (int i = 0; i < 4; ++i) {
      int m = m0 + wm + i * 16 + (lane & 15);
      if (m >= M) continue;
      size_t ro = (size_t)blockIdx.z * M + m;
#pragma unroll
      for (int j = 0; j < 4; ++j) {
        int nb = n0 + wn + j * 16 + (lane >> 4) * 4;
        float4 b4 = bias ? *(const float4*)&bias[nb] : make_float4(0.f, 0.f, 0.f, 0.f);
        *(float4*)((float*)Cout + ro * ldc + nb) =
            make_float4(acc[i][j][0] + b4.x, acc[i][j][1] + b4.y,
                        acc[i][j][2] + b4.z, acc[i][j][3] + b4.w);
      }
    }
  }
}

// ---------------------------------------------------------------- chain: fully LDS-staged I/O
__device__ __forceinline__ void block_red2(float& s, float& sq, float* redS,
                                           float* redQ, int tid) {
#pragma unroll
  for (int off = 32; off > 0; off >>= 1) {
    s += __shfl_down(s, off);
    sq += __shfl_down(sq, off);
  }
  int w = tid >> 6;
  if ((tid & 63) == 0) { redS[w] = s; redQ[w] = sq; }
  __syncthreads();
  s = redS[0] + redS[1] + redS[2] + redS[3];
  sq = redQ[0] + redQ[1] + redQ[2] + redQ[3];
}

// LDS layout (ushorts): Mt[64][72] @0 (4608) | Ss[128][40] @4608 (5120)
//                       xbs[32][72] @9728 (2304) | o1T[64][PPAD] @12032 (2688)
// O2[128][72] aliases @0 (max 9207 < 9728; Mt+Ss dead by then)
__global__ __launch_bounds__(256) void chain_k(
    const float* __restrict__ x, bf16* __restrict__ common) {
  int tid = threadIdx.x;
  int tl = blockIdx.x;
  int g = blockIdx.y;
  int lane = tid & 63, w = tid >> 6;

  __shared__ __align__(16) ushort sm[14720];  // 29.4 KB
  __shared__ float redS[4], redQ[4];
  ushort* Mt = sm;
  ushort* Ss = sm + 4608;
  ushort* xbs = sm + 9728;
  ushort* o1Tb = sm + 12032;

  bf16* cm = common + (size_t)tl * FLAT + g * GSZ;
  const ushort* cmu = (const ushort*)cm;
  const float* xg = x + ((size_t)tl * NG + g) * 2048;

  // ---- coalesced stage: M-part, S-part (16B/lane), x (fp32 -> bf16)
#pragma unroll
  for (int it = 0; it < 2; ++it) {
    int idx = it * 256 + tid;
    int e = idx * 8;
    { // M: [d][c] rows of 64
      bf16x8 v = *(const bf16x8*)&cmu[e];
      *(bf16x8*)&Mt[(e >> 6) * 72 + (e & 63)] = v;
    }
    { // S: [o][p] rows of 32
      bf16x8 v = *(const bf16x8*)&cmu[4096 + e];
      *(bf16x8*)&Ss[(e >> 5) * 40 + (e & 31)] = v;
    }
    { // x: [p][c] rows of 64, fp32->bf16
      int fi = it * 256 + tid;           // float4 index 0..511
      float4 v = ((const float4*)xg)[fi];
      int fl = fi * 4;
      ushort4 u = {f2u(v.x), f2u(v.y), f2u(v.z), f2u(v.w)};
      *(ushort4*)&xbs[(fl >> 6) * 72 + (fl & 63)] = u;
    }
  }
  __syncthreads();

  // ---- out1^T[d][p] = sum_c M^T[d][c] * x[p][c]
  int dlane = w * 16 + (lane & 15);
  f32x4 a1[2] = {};
#pragma unroll
  for (int ks = 0; ks < 2; ++ks) {
    bf16x8 af = *(const bf16x8*)&Mt[dlane * 72 + ks * 32 + (lane >> 4) * 8];
#pragma unroll
    for (int pt = 0; pt < 2; ++pt) {
      int p = pt * 16 + (lane & 15);
      bf16x8 bx = *(const bf16x8*)&xbs[p * 72 + ks * 32 + (lane >> 4) * 8];
      a1[pt] = __builtin_amdgcn_mfma_f32_16x16x32_bf16(af, bx, a1[pt], 0, 0, 0);
    }
  }
  // ---- LN1 over 2048 + relu -> o1^T bf16
  {
    float s = 0.f, sq = 0.f;
#pragma unroll
    for (int pt = 0; pt < 2; ++pt)
#pragma unroll
      for (int r = 0; r < 4; ++r) { float v = a1[pt][r]; s += v; sq += v * v; }
    block_red2(s, sq, redS, redQ, tid);
    float mean = s * (1.f / 2048.f);
    float var = sq * (1.f / 2048.f) - mean * mean;
    float rs = rsqrtf(var + LN_EPS);
#pragma unroll
    for (int pt = 0; pt < 2; ++pt)
#pragma unroll
      for (int r = 0; r < 4; ++r) {
        float v = (a1[pt][r] - mean) * rs;
        if (v < 0.f) v = 0.f;
        int d = w * 16 + (lane >> 4) * 4 + r;
        int p = pt * 16 + (lane & 15);
        o1Tb[d * PPAD + p] = f2u(v);
      }
  }
  __syncthreads();

  // ---- out2[o][d] = sum_p S[o][p] * o1^T[d][p]
  f32x4 a2[2][4] = {};
  {
    bf16x8 bfd[4];
#pragma unroll
    for (int dj = 0; dj < 4; ++dj)
      bfd[dj] = *(const bf16x8*)&o1Tb[(dj * 16 + (lane & 15)) * PPAD + (lane >> 4) * 8];
#pragma unroll
    for (int oi = 0; oi < 2; ++oi) {
      int o = (2 * w + oi) * 16 + (lane & 15);
      bf16x8 sf = *(const bf16x8*)&Ss[o * 40 + (lane >> 4) * 8];
#pragma unroll
      for (int dj = 0; dj < 4; ++dj)
        a2[oi][dj] = __builtin_amdgcn_mfma_f32_16x16x32_bf16(bfd[dj], sf, a2[oi][dj], 0, 0, 0);
    }
  }
  // ---- LN2 over 8192 + relu -> O2 LDS (aliases Mt/Ss) -> coalesced global write
  {
    float s = 0.f, sq = 0.f;
#pragma unroll
    for (int oi = 0; oi < 2; ++oi)
#pragma unroll
      for (int dj = 0; dj < 4; ++dj)
#pragma unroll
        for (int r = 0; r < 4; ++r) { float v = a2[oi][dj][r]; s += v; sq += v * v; }
    block_red2(s, sq, redS, redQ, tid);   // internal barrier: all Ss reads complete after this
    float mean = s * (1.f / 8192.f);
    float var = sq * (1.f / 8192.f) - mean * mean;
    float rs = rsqrtf(var + LN_EPS);
#pragma unroll
    for (int oi = 0; oi < 2; ++oi) {
      int o = (2 * w + oi) * 16 + (lane & 15);
#pragma unroll
      for (int dj = 0; dj < 4; ++dj) {
        int d0 = dj * 16 + (lane >> 4) * 4;
        ushort4 uv;
#pragma unroll
        for (int r = 0; r < 4; ++r) {
          float v = (a2[oi][dj][r] - mean) * rs;
          if (v < 0.f) v = 0.f;
          ((ushort*)&uv)[r] = f2u(v);
        }
        *(ushort4*)&sm[o * 72 + d0] = uv;   // O2[o][d] @ base 0
      }
    }
  }
  __syncthreads();
  {
    // write ALL 8192 ushorts of out2 (128 rows x 64 cols)
    ushort* cw = (ushort*)cm;
#pragma unroll
    for (int it = 0; it < 4; ++it) {
      int e = (it * 256 + tid) * 8;
      *(bf16x8*)&cw[e] = *(const bf16x8*)&sm[(e >> 6) * 72 + (e & 63)];
    }
  }
}

// ---------------------------------------------------------------- finish
__global__ __launch_bounds__(256) void finish_k(
    const float* __restrict__ partial, const float* __restrict__ query,
    const float* __restrict__ out_bias, const float* __restrict__ gamma,
    const float* __restrict__ beta, float* __restrict__ out, int t0, int M) {
  int tid = threadIdx.x;
  int tl = blockIdx.x;
  int t = t0 + tl;
  __shared__ float redS[4], redQ[4];
  float s = 0.f;
  for (int ks = 0; ks < KSP; ++ks)
    s += partial[((size_t)ks * M + tl) * QDIM + tid];
  float v = s + out_bias[tid] + query[(size_t)t * QDIM + tid];
  float sum = v, sqv = v * v;
  block_red2(sum, sqv, redS, redQ, tid);
  float mean = sum * (1.f / 256.f);
  float var = sqv * (1.f / 256.f) - mean * mean;
  out[(size_t)t * QDIM + tid] =
      (v - mean) * rsqrtf(var + LN_EPS) * gamma[tid] + beta[tid];
}

// ---------------------------------------------------------------- launch
extern "C" void kernel_launch(void* const* d_in, const int* in_sizes, int n_in,
                              void* d_out, int out_size, void* d_ws, size_t ws_size,
                              hipStream_t stream) {
  const float* x       = (const float*)d_in[1];
  const float* query   = (const float*)d_in[2];
  const float* cpg_w   = (const float*)d_in[3];
  const float* cpg_b   = (const float*)d_in[4];
  const float* ppg_w   = (const float*)d_in[5];
  const float* ppg_b   = (const float*)d_in[6];
  const float* ml      = (const float*)d_in[7];
  const float* mr      = (const float*)d_in[8];
  const float* sl      = (const float*)d_in[9];
  const float* sr      = (const float*)d_in[10];
  const float* base_w  = (const float*)d_in[11];
  const float* lora_A  = (const float*)d_in[12];
  const float* lora_B  = (const float*)d_in[13];
  const float* out_bias= (const float*)d_in[14];
  const float* gamma   = (const float*)d_in[15];
  const float* beta    = (const float*)d_in[16];
  float* out = (float*)d_out;

  float* wsf = (float*)d_ws;
  bf16*  Wb      = (bf16*)(wsf + 0);          // 256x32768 bf16 = 4,194,304 f
  bf16*  Weff    = (bf16*)(wsf + 4194304);    // 32768x256 bf16 = 4,194,304 f
  float* bias_eff= wsf + 8388608;             // 32,768 f
  bf16*  qb      = (bf16*)(wsf + 8421376);    // 2400x256 bf16 = 307,200 f
  size_t fixedF  = 8728576;
  int CT = (ws_size >= (fixedF + (size_t)BN_TOK * 20480) * sizeof(float)) ? BN_TOK : 600;
  int NCH = BN_TOK / CT;
  bf16*  commonb = (bf16*)(wsf + fixedF);
  float* partialb= wsf + fixedF + (size_t)CT * 16384;

  // prep (once per call)
  build_weff_k<<<dim3(64, NG, 2), 256, 0, stream>>>(
      cpg_w, cpg_b, ppg_w, ppg_b, ml, mr, sl, sr, Weff, bias_eff);
  cast_k<<<dim3(BN_TOK * QDIM / 4 / 256), 256, 0, stream>>>(query, qb, BN_TOK * QDIM / 4);
  build_wb_k<<<dim3(FLAT / 256, QDIM / 16), 256, 0, stream>>>(base_w, lora_A, lora_B, Wb);

  for (int ch = 0; ch < NCH; ++ch) {
    int t0 = ch * CT;
    gemm_nt<true><<<dim3((CT + 127) / 128, FLAT / 128, 1), 256, 0, stream>>>(
        qb + (size_t)t0 * QDIM, Weff, bias_eff, commonb, CT, QDIM, QDIM, QDIM, FLAT);
    chain_k<<<dim3(CT, NG), 256, 0, stream>>>(x + (size_t)t0 * GSZ, commonb);
    gemm_nt<false><<<dim3((CT + 127) / 128, QDIM / 128, KSP), 256, 0, stream>>>(
        commonb, Wb, nullptr, partialb, CT, FLAT, FLAT, FLAT / KSP, QDIM);
    finish_k<<<dim3(CT), 256, 0, stream>>>(partialb, query, out_bias, gamma, beta, out, t0, CT);
  }
}